// Round 1
// baseline (72.098 us; speedup 1.0000x reference)
//
#include <hip/hip_runtime.h>
#include <hip/hip_bf16.h>
#include <stdint.h>

#define NROWS 4096
#define FIN   256
#define NHEADS 8
#define NFEAT 64
#define HF    512          // HEADS*FEAT
#define NEG   0.2f
#define MAXDEG 256

__device__ __forceinline__ float bflo(uint32_t v) { return __uint_as_float(v << 16); }
__device__ __forceinline__ float bfhi(uint32_t v) { return __uint_as_float(v & 0xffff0000u); }
__device__ __forceinline__ uint16_t f2bf(float f) {
    uint32_t u = __float_as_uint(f);
    u += 0x7fffu + ((u >> 16) & 1u);   // round-to-nearest-even
    return (uint16_t)(u >> 16);
}

// ---------------- Kernel 1: h = x @ W (fp32), also bf16 copy ----------------
// Tile 64x64, BK=16, 256 threads, 4x4 micro-tile per thread.
__global__ __launch_bounds__(256) void k_gemm(const float* __restrict__ x,
                                              const float* __restrict__ W,
                                              float* __restrict__ h32,
                                              uint16_t* __restrict__ hbf) {
    __shared__ __align__(16) float As[16][68];  // [k][m], padded
    __shared__ __align__(16) float Bs[16][68];  // [k][n], padded
    const int t  = threadIdx.x;
    const int bm = blockIdx.x >> 3;   // 0..63 row tile
    const int bn = blockIdx.x & 7;    // 0..7 col tile
    const int ty = t >> 4, tx = t & 15;

    const int am  = t >> 2;           // 0..63
    const int ak4 = (t & 3) << 2;     // 0,4,8,12
    const int bk  = t >> 4;           // 0..15
    const int bn4 = (t & 15) << 2;    // 0..60

    float acc[4][4] = {};

    for (int kt = 0; kt < FIN; kt += 16) {
        float4 av = *(const float4*)&x[(size_t)(bm*64 + am)*FIN + kt + ak4];
        float4 bv = *(const float4*)&W[(size_t)(kt + bk)*HF + bn*64 + bn4];
        __syncthreads();
        As[ak4+0][am] = av.x; As[ak4+1][am] = av.y;
        As[ak4+2][am] = av.z; As[ak4+3][am] = av.w;
        *(float4*)&Bs[bk][bn4] = bv;
        __syncthreads();
        #pragma unroll
        for (int k = 0; k < 16; ++k) {
            float4 a = *(const float4*)&As[k][ty*4];
            float4 b = *(const float4*)&Bs[k][tx*4];
            float ar[4] = {a.x, a.y, a.z, a.w};
            float br[4] = {b.x, b.y, b.z, b.w};
            #pragma unroll
            for (int r = 0; r < 4; ++r)
                #pragma unroll
                for (int c = 0; c < 4; ++c)
                    acc[r][c] += ar[r] * br[c];
        }
    }

    #pragma unroll
    for (int r = 0; r < 4; ++r) {
        int row = bm*64 + ty*4 + r;
        int col = bn*64 + tx*4;
        *(float4*)&h32[(size_t)row*HF + col] =
            make_float4(acc[r][0], acc[r][1], acc[r][2], acc[r][3]);
        ushort4 u;
        u.x = f2bf(acc[r][0]); u.y = f2bf(acc[r][1]);
        u.z = f2bf(acc[r][2]); u.w = f2bf(acc[r][3]);
        *(ushort4*)&hbf[(size_t)row*HF + col] = u;
    }
}

// ---------------- Kernel 2: s_src/s_dst = h . a ----------------
// 1 wave per row, 4 rows per block.
__global__ __launch_bounds__(256) void k_scores(const float* __restrict__ h32,
                                                const float* __restrict__ a_src,
                                                const float* __restrict__ a_dst,
                                                float* __restrict__ s_src,
                                                float* __restrict__ s_dst) {
    const int wave = threadIdx.x >> 6;
    const int lane = threadIdx.x & 63;
    const int row  = blockIdx.x * 4 + wave;
    const float asf = a_src[lane];
    const float adf = a_dst[lane];
    const float* hr = h32 + (size_t)row * HF;
    #pragma unroll
    for (int h = 0; h < NHEADS; ++h) {
        float v = hr[h*64 + lane];
        float ps = v * asf, pd = v * adf;
        #pragma unroll
        for (int m = 32; m > 0; m >>= 1) {
            ps += __shfl_xor(ps, m);
            pd += __shfl_xor(pd, m);
        }
        if (lane == 0) {
            s_src[row*NHEADS + h] = ps;
            s_dst[row*NHEADS + h] = pd;
        }
    }
}

// ---------------- Kernel 3: per-row sparse softmax + aggregation ----------------
__global__ __launch_bounds__(256) void k_gat(const float* __restrict__ adj,
                                             const float* __restrict__ s_src,
                                             const float* __restrict__ s_dst,
                                             const uint16_t* __restrict__ hbf,
                                             float* __restrict__ out) {
    __shared__ uint16_t nbr[MAXDEG];
    __shared__ float ebuf[MAXDEG][NHEADS];
    __shared__ int   sc[256];
    __shared__ float ssrc_i[NHEADS];
    __shared__ float hred[4][NHEADS];
    __shared__ float hmax[NHEADS], hinv[NHEADS];

    const int i = blockIdx.x;
    const int t = threadIdx.x;

    if (t < NHEADS) ssrc_i[t] = s_src[i*NHEADS + t];

    // ---- phase 1: deterministic compaction of adj row ----
    const float* arow = adj + (size_t)i * NROWS;
    float v[16];
    #pragma unroll
    for (int q = 0; q < 4; ++q) {
        float4 f = *(const float4*)&arow[t*16 + q*4];
        v[q*4+0] = f.x; v[q*4+1] = f.y; v[q*4+2] = f.z; v[q*4+3] = f.w;
    }
    int cnt = 0;
    #pragma unroll
    for (int q = 0; q < 16; ++q) {
        int j = t*16 + q;
        if (v[q] != 0.f || j == i) cnt++;
    }
    sc[t] = cnt;
    __syncthreads();
    // inclusive block scan (Hillis-Steele)
    for (int d = 1; d < 256; d <<= 1) {
        int add = (t >= d) ? sc[t - d] : 0;
        __syncthreads();
        sc[t] += add;
        __syncthreads();
    }
    int off = sc[t] - cnt;
    int total = sc[255];
    if (total > MAXDEG) total = MAXDEG;   // statistically impossible; memory safety
    #pragma unroll
    for (int q = 0; q < 16; ++q) {
        int j = t*16 + q;
        if (v[q] != 0.f || j == i) {
            if (off < MAXDEG) nbr[off] = (uint16_t)j;
            off++;
        }
    }
    __syncthreads();

    // ---- phase 2: e = leaky_relu(s_src[i,h] + s_dst[j,h]) ----
    for (int p = t; p < total; p += 256) {
        int j = nbr[p];
        const float* sd = s_dst + j*NHEADS;
        #pragma unroll
        for (int h = 0; h < NHEADS; ++h) {
            float e = ssrc_i[h] + sd[h];
            e = (e > 0.f) ? e : NEG * e;
            ebuf[p][h] = e;
        }
    }
    __syncthreads();

    // ---- phase 2b: per-head max, then sum of exp (32 threads per head) ----
    {
        const int h = t & 7, idx = t >> 3;
        const int w = t >> 6;
        float m = -1e30f;
        for (int p = idx; p < total; p += 32) m = fmaxf(m, ebuf[p][h]);
        #pragma unroll
        for (int msk = 8; msk < 64; msk <<= 1) m = fmaxf(m, __shfl_xor(m, msk));
        if ((t & 63) < 8) hred[w][t & 7] = m;
        __syncthreads();
        if (t < NHEADS) {
            hmax[t] = fmaxf(fmaxf(hred[0][t], hred[1][t]),
                            fmaxf(hred[2][t], hred[3][t]));
        }
        __syncthreads();
        const float mh = hmax[h];
        float s = 0.f;
        for (int p = idx; p < total; p += 32) {
            float ev = __expf(ebuf[p][h] - mh);
            ebuf[p][h] = ev;     // store unnormalized alpha
            s += ev;
        }
        #pragma unroll
        for (int msk = 8; msk < 64; msk <<= 1) s += __shfl_xor(s, msk);
        if ((t & 63) < 8) hred[w][t & 7] = s;
        __syncthreads();
        if (t < NHEADS)
            hinv[t] = 1.f / (hred[0][t] + hred[1][t] + hred[2][t] + hred[3][t]);
        __syncthreads();
    }

    // ---- phase 3: out[i, 2t..2t+1] = (1/sum) * sum_p alpha[p,h] * hbf[j_p, 2t..2t+1]
    const int h = t >> 5;                 // head of outputs 2t,2t+1
    const float inv = hinv[h];
    float acc0 = 0.f, acc1 = 0.f;
    const uint32_t* hb = (const uint32_t*)hbf;
    int p = 0;
    for (; p + 4 <= total; p += 4) {
        #pragma unroll
        for (int u = 0; u < 4; ++u) {
            int j = nbr[p + u];
            uint32_t wv = hb[(size_t)j*256 + t];
            float a = ebuf[p + u][h];
            acc0 += a * bflo(wv);
            acc1 += a * bfhi(wv);
        }
    }
    for (; p < total; ++p) {
        int j = nbr[p];
        uint32_t wv = hb[(size_t)j*256 + t];
        float a = ebuf[p][h];
        acc0 += a * bflo(wv);
        acc1 += a * bfhi(wv);
    }
    *(float2*)&out[(size_t)i*HF + 2*t] = make_float2(acc0*inv, acc1*inv);
}

extern "C" void kernel_launch(void* const* d_in, const int* in_sizes, int n_in,
                              void* d_out, int out_size, void* d_ws, size_t ws_size,
                              hipStream_t stream) {
    const float* x     = (const float*)d_in[0];
    const float* adj   = (const float*)d_in[1];
    const float* W     = (const float*)d_in[2];
    const float* a_src = (const float*)d_in[3];
    const float* a_dst = (const float*)d_in[4];
    float* out = (float*)d_out;

    char* ws = (char*)d_ws;
    float*    h32   = (float*)ws;                                   // 8 MB
    uint16_t* hbf   = (uint16_t*)(ws + 8u*1024*1024);               // 4 MB
    float*    s_src = (float*)(ws + 12u*1024*1024);                 // 128 KB
    float*    s_dst = (float*)(ws + 12u*1024*1024 + 128u*1024);     // 128 KB

    k_gemm  <<<512,  256, 0, stream>>>(x, W, h32, hbf);
    k_scores<<<1024, 256, 0, stream>>>(h32, a_src, a_dst, s_src, s_dst);
    k_gat   <<<4096, 256, 0, stream>>>(adj, s_src, s_dst, hbf, out);
}

// Round 2
// 57.351 us; speedup vs baseline: 1.2571x; 1.2571x over previous
//
#include <hip/hip_runtime.h>
#include <hip/hip_bf16.h>
#include <stdint.h>

#define NROWS 4096
#define FIN   256
#define NHEADS 8
#define NFEAT 64
#define HF    512          // HEADS*FEAT
#define NEG   0.2f
#define MAXDEG 256

__device__ __forceinline__ float bflo(uint32_t v) { return __uint_as_float(v << 16); }
__device__ __forceinline__ float bfhi(uint32_t v) { return __uint_as_float(v & 0xffff0000u); }
__device__ __forceinline__ uint16_t f2bf(float f) {
    uint32_t u = __float_as_uint(f);
    u += 0x7fffu + ((u >> 16) & 1u);   // round-to-nearest-even
    return (uint16_t)(u >> 16);
}

// ---------------- Kernel 1: h = x @ W, bf16 out + fused s_src/s_dst scores ----
// Tile 64x64, BK=16, 256 threads, 4x4 micro-tile per thread. Head == bn tile.
__global__ __launch_bounds__(256) void k_gemm(const float* __restrict__ x,
                                              const float* __restrict__ W,
                                              const float* __restrict__ a_src,
                                              const float* __restrict__ a_dst,
                                              uint16_t* __restrict__ hbf,
                                              float* __restrict__ s_src,
                                              float* __restrict__ s_dst) {
    __shared__ __align__(16) float As[16][68];  // [k][m], padded
    __shared__ __align__(16) float Bs[16][68];  // [k][n], padded
    const int t  = threadIdx.x;
    const int bm = blockIdx.x >> 3;   // 0..63 row tile
    const int bn = blockIdx.x & 7;    // 0..7 col tile == head
    const int ty = t >> 4, tx = t & 15;

    const int am  = t >> 2;           // 0..63
    const int ak4 = (t & 3) << 2;     // 0,4,8,12
    const int bk  = t >> 4;           // 0..15
    const int bn4 = (t & 15) << 2;    // 0..60

    float acc[4][4] = {};

    for (int kt = 0; kt < FIN; kt += 16) {
        float4 av = *(const float4*)&x[(size_t)(bm*64 + am)*FIN + kt + ak4];
        float4 bv = *(const float4*)&W[(size_t)(kt + bk)*HF + bn*64 + bn4];
        __syncthreads();
        As[ak4+0][am] = av.x; As[ak4+1][am] = av.y;
        As[ak4+2][am] = av.z; As[ak4+3][am] = av.w;
        *(float4*)&Bs[bk][bn4] = bv;
        __syncthreads();
        #pragma unroll
        for (int k = 0; k < 16; ++k) {
            float4 a = *(const float4*)&As[k][ty*4];
            float4 b = *(const float4*)&Bs[k][tx*4];
            float ar[4] = {a.x, a.y, a.z, a.w};
            float br[4] = {b.x, b.y, b.z, b.w};
            #pragma unroll
            for (int r = 0; r < 4; ++r)
                #pragma unroll
                for (int c = 0; c < 4; ++c)
                    acc[r][c] += ar[r] * br[c];
        }
    }

    // bf16 h store
    #pragma unroll
    for (int r = 0; r < 4; ++r) {
        int row = bm*64 + ty*4 + r;
        int col = bn*64 + tx*4;
        ushort4 u;
        u.x = f2bf(acc[r][0]); u.y = f2bf(acc[r][1]);
        u.z = f2bf(acc[r][2]); u.w = f2bf(acc[r][3]);
        *(ushort4*)&hbf[(size_t)row*HF + col] = u;
    }

    // fused score epilogue: reduce over the 64 feature cols of head bn.
    // feature index within head = tx*4 + c
    float4 avs = *(const float4*)&a_src[tx*4];
    float4 avd = *(const float4*)&a_dst[tx*4];
    #pragma unroll
    for (int r = 0; r < 4; ++r) {
        float ps = acc[r][0]*avs.x + acc[r][1]*avs.y + acc[r][2]*avs.z + acc[r][3]*avs.w;
        float pd = acc[r][0]*avd.x + acc[r][1]*avd.y + acc[r][2]*avd.z + acc[r][3]*avd.w;
        #pragma unroll
        for (int msk = 1; msk < 16; msk <<= 1) {
            ps += __shfl_xor(ps, msk);
            pd += __shfl_xor(pd, msk);
        }
        if (tx == 0) {
            int row = bm*64 + ty*4 + r;
            s_src[row*NHEADS + bn] = ps;
            s_dst[row*NHEADS + bn] = pd;
        }
    }
}

// ---------------- Kernel 2: per-row sparse softmax + aggregation ----------------
// 128 threads (2 waves) per row. Wave-ballot-free compaction via popcount scan.
__global__ __launch_bounds__(128) void k_gat(const float* __restrict__ adj,
                                             const float* __restrict__ s_src,
                                             const float* __restrict__ s_dst,
                                             const uint16_t* __restrict__ hbf,
                                             float* __restrict__ out) {
    __shared__ uint16_t nbr[MAXDEG];
    __shared__ float ebuf[MAXDEG][NHEADS];
    __shared__ float ssrc_i[NHEADS];
    __shared__ int   wcnt[2];
    __shared__ float hred[2][NHEADS];
    __shared__ float hmax[NHEADS], hinv[NHEADS];

    const int i = blockIdx.x;
    const int t = threadIdx.x;
    const int w = t >> 6, lane = t & 63;

    if (t < NHEADS) ssrc_i[t] = s_src[i*NHEADS + t];

    // ---- phase 1: predicate mask for this thread's 32 contiguous adj elems ----
    const float* arow = adj + (size_t)i * NROWS;
    uint32_t pm = 0;
    #pragma unroll
    for (int q4 = 0; q4 < 8; ++q4) {
        float4 f = *(const float4*)&arow[t*32 + q4*4];
        if (f.x != 0.f) pm |= 1u << (q4*4+0);
        if (f.y != 0.f) pm |= 1u << (q4*4+1);
        if (f.z != 0.f) pm |= 1u << (q4*4+2);
        if (f.w != 0.f) pm |= 1u << (q4*4+3);
    }
    if ((i >> 5) == t) pm |= 1u << (i & 31);   // self loop

    int pcnt = __popc(pm);
    // inclusive scan of pcnt over the 64 lanes of this wave (no LDS, no barrier)
    int incl = pcnt;
    #pragma unroll
    for (int d = 1; d < 64; d <<= 1) {
        int u = __shfl_up(incl, d);
        if (lane >= d) incl += u;
    }
    if (lane == 63) wcnt[w] = incl;
    __syncthreads();
    const int base0 = wcnt[0];
    int total = base0 + wcnt[1];
    if (total > MAXDEG) total = MAXDEG;        // statistically impossible; safety
    int pos = ((w == 0) ? 0 : base0) + incl - pcnt;

    // ---- write compacted neighbor list + fused e = leaky_relu(s_i + s_j) ----
    uint32_t m = pm;
    while (m) {
        int q = __ffs(m) - 1;  m &= m - 1;
        int j = t*32 + q;
        if (pos < MAXDEG) {
            nbr[pos] = (uint16_t)j;
            float4 d0 = *(const float4*)&s_dst[j*NHEADS];
            float4 d1 = *(const float4*)&s_dst[j*NHEADS + 4];
            float e0 = ssrc_i[0] + d0.x; ebuf[pos][0] = e0 > 0.f ? e0 : NEG*e0;
            float e1 = ssrc_i[1] + d0.y; ebuf[pos][1] = e1 > 0.f ? e1 : NEG*e1;
            float e2 = ssrc_i[2] + d0.z; ebuf[pos][2] = e2 > 0.f ? e2 : NEG*e2;
            float e3 = ssrc_i[3] + d0.w; ebuf[pos][3] = e3 > 0.f ? e3 : NEG*e3;
            float e4 = ssrc_i[4] + d1.x; ebuf[pos][4] = e4 > 0.f ? e4 : NEG*e4;
            float e5 = ssrc_i[5] + d1.y; ebuf[pos][5] = e5 > 0.f ? e5 : NEG*e5;
            float e6 = ssrc_i[6] + d1.z; ebuf[pos][6] = e6 > 0.f ? e6 : NEG*e6;
            float e7 = ssrc_i[7] + d1.w; ebuf[pos][7] = e7 > 0.f ? e7 : NEG*e7;
        }
        pos++;
    }
    __syncthreads();

    // ---- phase 2: per-head max then sum of exp (16 threads per head) ----
    const int hh = t & 7, idx = t >> 3;        // idx 0..15 across both waves
    float mx = -1e30f;
    for (int p = idx; p < total; p += 16) mx = fmaxf(mx, ebuf[p][hh]);
    #pragma unroll
    for (int msk = 8; msk < 64; msk <<= 1) mx = fmaxf(mx, __shfl_xor(mx, msk));
    if (lane < NHEADS) hred[w][lane] = mx;
    __syncthreads();
    if (t < NHEADS) hmax[t] = fmaxf(hred[0][t], hred[1][t]);
    __syncthreads();

    const float mh = hmax[hh];
    float s = 0.f;
    for (int p = idx; p < total; p += 16) {
        float ev = __expf(ebuf[p][hh] - mh);
        ebuf[p][hh] = ev;                       // store unnormalized alpha
        s += ev;
    }
    #pragma unroll
    for (int msk = 8; msk < 64; msk <<= 1) s += __shfl_xor(s, msk);
    if (lane < NHEADS) hred[w][lane] = s;
    __syncthreads();
    if (t < NHEADS) hinv[t] = 1.f / (hred[0][t] + hred[1][t]);
    __syncthreads();

    // ---- phase 3: out[i, 4t..4t+3] = inv * sum_p alpha[p,h] * hbf[j_p, 4t..4t+3]
    const int h3 = t >> 4;                     // head of this thread's 4 cols
    const float inv = hinv[h3];
    const uint2* hb2 = (const uint2*)hbf;
    float a0 = 0.f, a1 = 0.f, a2 = 0.f, a3 = 0.f;
    int p = 0;
    for (; p + 4 <= total; p += 4) {
        #pragma unroll
        for (int u = 0; u < 4; ++u) {
            int j = nbr[p + u];
            uint2 wv = hb2[(size_t)j*128 + t];
            float a = ebuf[p + u][h3];
            a0 += a * bflo(wv.x); a1 += a * bfhi(wv.x);
            a2 += a * bflo(wv.y); a3 += a * bfhi(wv.y);
        }
    }
    for (; p < total; ++p) {
        int j = nbr[p];
        uint2 wv = hb2[(size_t)j*128 + t];
        float a = ebuf[p][h3];
        a0 += a * bflo(wv.x); a1 += a * bfhi(wv.x);
        a2 += a * bflo(wv.y); a3 += a * bfhi(wv.y);
    }
    *(float4*)&out[(size_t)i*HF + t*4] = make_float4(a0*inv, a1*inv, a2*inv, a3*inv);
}

extern "C" void kernel_launch(void* const* d_in, const int* in_sizes, int n_in,
                              void* d_out, int out_size, void* d_ws, size_t ws_size,
                              hipStream_t stream) {
    const float* x     = (const float*)d_in[0];
    const float* adj   = (const float*)d_in[1];
    const float* W     = (const float*)d_in[2];
    const float* a_src = (const float*)d_in[3];
    const float* a_dst = (const float*)d_in[4];
    float* out = (float*)d_out;

    char* ws = (char*)d_ws;
    uint16_t* hbf   = (uint16_t*)ws;                                // 4 MB
    float*    s_src = (float*)(ws + 4u*1024*1024);                  // 128 KB
    float*    s_dst = (float*)(ws + 4u*1024*1024 + 128u*1024);      // 128 KB

    k_gemm<<<512,  256, 0, stream>>>(x, W, a_src, a_dst, hbf, s_src, s_dst);
    k_gat <<<4096, 128, 0, stream>>>(adj, s_src, s_dst, hbf, out);
}